// Round 7
// baseline (1692.839 us; speedup 1.0000x reference)
//
#include <hip/hip_runtime.h>
#include <hip/hip_fp16.h>
#include <stdint.h>

#define N_NODES 100000
#define N_EDGES 3200000
#define QCH 32
#define QP (QCH / 2)
#define DT_C 0.1f

#define BUCKET_SHIFT 6
#define BUCKET_NODES 64
#define NB 1563                 // ceil(100000/64)
#define CAP 4608                // mean 4096 + 8 sigma, multiple of 128
#define BIN_BLOCKS 256
#define EPB 12500               // 256 * 12500 = 3.2M edges exactly
#define GDEEP 16                // records per half-wave per iteration

// ---------------- binned-gather path ----------------

__global__ void deg_kernel_u32(const int* __restrict__ src,
                               unsigned int* __restrict__ deg, int E) {
    int e = blockIdx.x * blockDim.x + threadIdx.x;
    if (e < E) atomicAdd(&deg[src[e]], 1u);
}

// fp16 copy of relu(f): halves gather row bytes, hoists relu out of hot loop
__global__ void fh_kernel(const float2* __restrict__ f2,
                          __half2* __restrict__ fh, int n2) {
    int i = blockIdx.x * blockDim.x + threadIdx.x;
    if (i < n2) {
        float2 v = f2[i];
        fh[i] = __floats2half2_rn(fmaxf(v.x, 0.0f), fmaxf(v.y, 0.0f));
    }
}

// per-block LDS histogram -> global range alloc -> clustered scatter (+csum)
__global__ __launch_bounds__(256) void bin_kernel(
        const int* __restrict__ src,
        const int* __restrict__ dst,
        const float* __restrict__ w,
        const unsigned int* __restrict__ deg,
        unsigned int* __restrict__ gcur,     // [NB], zeroed
        unsigned int* __restrict__ keys,     // [NB*CAP]
        __half* __restrict__ coefs,          // [NB*CAP]
        float* __restrict__ csum,            // [N], zeroed
        int E) {
    __shared__ unsigned int hist[NB];
    __shared__ unsigned int base[NB];
    int tid = threadIdx.x;
    int b0 = blockIdx.x * EPB;
    int b1 = min(b0 + EPB, E);

    for (int i = tid; i < NB; i += 256) hist[i] = 0;
    __syncthreads();

    for (int e = b0 + tid; e < b1; e += 256) {
        int s = src[e], d = dst[e];
        atomicAdd(&hist[s >> BUCKET_SHIFT], 1u);
        atomicAdd(&hist[d >> BUCKET_SHIFT], 1u);
    }
    __syncthreads();

    for (int i = tid; i < NB; i += 256) {
        unsigned int c = hist[i];
        base[i] = c ? atomicAdd(&gcur[i], c) : 0u;
        hist[i] = 0u;            // reuse as running cursor
    }
    __syncthreads();

    for (int e = b0 + tid; e < b1; e += 256) {
        int s = src[e], d = dst[e];
        float c = w[e] / fmaxf((float)deg[s], 1.0f);
        atomicAdd(&csum[s], c);
        atomicAdd(&csum[d], c);
        __half ch = __float2half(c);
        unsigned int bs = (unsigned int)s >> BUCKET_SHIFT;
        unsigned int o1 = atomicAdd(&hist[bs], 1u) + base[bs];
        if (o1 < CAP) {
            unsigned int pos = bs * CAP + o1;
            keys[pos] = ((unsigned int)s & 63u) | ((unsigned int)d << 6);
            coefs[pos] = ch;
        }
        unsigned int bd = (unsigned int)d >> BUCKET_SHIFT;
        unsigned int o2 = atomicAdd(&hist[bd], 1u) + base[bd];
        if (o2 < CAP) {
            unsigned int pos = bd * CAP + o2;
            keys[pos] = ((unsigned int)d & 63u) | ((unsigned int)s << 6);
            coefs[pos] = ch;
        }
    }
}

// pad each bucket to a multiple of 128 records with zero-coef records so the
// gather hot loop has no tail. Also clamps cnt to CAP.
__global__ void pad_kernel(unsigned int* __restrict__ gcur,
                           unsigned int* __restrict__ keys,
                           __half* __restrict__ coefs) {
    int b = blockIdx.x;
    unsigned int c = gcur[b];
    if (c > CAP) c = CAP;
    unsigned int cpad = (c + 127u) & ~127u;      // <= CAP since CAP%128==0
    unsigned int nbr = (unsigned int)(b * BUCKET_NODES);  // valid node id
    for (unsigned int i = c + threadIdx.x; i < cpad; i += 128) {
        keys[(size_t)b * CAP + i] = (nbr << 6);  // local=0, coef=0
        coefs[(size_t)b * CAP + i] = __float2half(0.0f);
    }
    if (threadIdx.x == 0) gcur[b] = cpad;
}

union CoefPack16 { uint4 u[2]; __half h[16]; };

// One block per bucket, 8 half-waves, 16 records per half-wave per iteration.
// Row loads issued via inline asm (guaranteed in-flight), one vmcnt(0) per
// group -> MLP=16 per half-wave instead of compiler-serialized MLP=1.
__global__ __launch_bounds__(256) void gather_kernel(
        const float* __restrict__ f,
        const __half* __restrict__ fh,       // relu'd fp16 rows
        const float* __restrict__ coll,
        const float* __restrict__ srct,
        const unsigned int* __restrict__ gcur,
        const unsigned int* __restrict__ keys,
        const __half* __restrict__ coefs,
        const float* __restrict__ csum,
        float* __restrict__ out) {
    __shared__ float acc[BUCKET_NODES * QCH];   // 8 KB
    int tid = threadIdx.x;
    int b = blockIdx.x;

    for (int i = tid; i < BUCKET_NODES * QCH; i += 256) acc[i] = 0.0f;
    __syncthreads();

    unsigned int cnt = gcur[b];                  // multiple of 128, <= CAP
    const unsigned int* bk = keys + (size_t)b * CAP;
    const __half* bc = coefs + (size_t)b * CAP;

    int q = tid & 31;           // q channel
    int hw = tid >> 5;          // half-wave 0..7

    unsigned int base2 = hw * GDEEP;
    if (base2 < cnt) {
        // prologue: load group 0 keys+coefs
        uint4 k0 = *(const uint4*)(bk + base2);
        uint4 k1 = *(const uint4*)(bk + base2 + 4);
        uint4 k2 = *(const uint4*)(bk + base2 + 8);
        uint4 k3 = *(const uint4*)(bk + base2 + 12);
        CoefPack16 cc;
        cc.u[0] = *(const uint4*)(bc + base2);
        cc.u[1] = *(const uint4*)(bc + base2 + 8);

        for (;;) {
            unsigned int nxt = base2 + 8 * GDEEP;
            bool has = nxt < cnt;
            uint4 nk0, nk1, nk2, nk3, nc0, nc1;
            if (has) {           // prefetch next group's keys (hidden under rows)
                nk0 = *(const uint4*)(bk + nxt);
                nk1 = *(const uint4*)(bk + nxt + 4);
                nk2 = *(const uint4*)(bk + nxt + 8);
                nk3 = *(const uint4*)(bk + nxt + 12);
                nc0 = *(const uint4*)(bc + nxt);
                nc1 = *(const uint4*)(bc + nxt + 8);
            }
            unsigned int kk[GDEEP] = {k0.x, k0.y, k0.z, k0.w,
                                      k1.x, k1.y, k1.z, k1.w,
                                      k2.x, k2.y, k2.z, k2.w,
                                      k3.x, k3.y, k3.z, k3.w};
            unsigned int rr[GDEEP];
#pragma unroll
            for (int j = 0; j < GDEEP; ++j) {
                const __half* ap = fh + (size_t)(kk[j] >> 6) * QCH + q;
                asm volatile("global_load_ushort %0, %1, off"
                             : "=&v"(rr[j]) : "v"(ap));
            }
            asm volatile("s_waitcnt vmcnt(0)" ::: "memory");
            __builtin_amdgcn_sched_barrier(0);
#pragma unroll
            for (int j = 0; j < GDEEP; ++j) {
                __half2 hv = *reinterpret_cast<__half2*>(&rr[j]);
                float fv = __low2float(hv);          // low 16 bits = value
                atomicAdd(&acc[(kk[j] & 63u) * QCH + q],
                          __half2float(cc.h[j]) * fv);
            }
            if (!has) break;
            base2 = nxt;
            k0 = nk0; k1 = nk1; k2 = nk2; k3 = nk3;
            cc.u[0] = nc0; cc.u[1] = nc1;
        }
    }
    __syncthreads();

    for (int i = tid; i < BUCKET_NODES * QCH; i += 256) {
        int local = i >> 5;
        int qq = i & 31;
        int node = b * BUCKET_NODES + local;
        if (node < N_NODES) {
            int idx = node * QCH + qq;
            float fn = fmaxf(f[idx], 0.0f);
            float xi = (75.0f / 31.0f) * (float)qq;
            float tr = xi * (acc[i] - fn * csum[node]);
            out[idx] = fmaxf(fn - DT_C * (tr - coll[idx] - srct[idx]), 0.0f);
        }
    }
}

// ---------------- fallback: proven r2 atomic path ----------------

__global__ void deg_kernel_f(const int* __restrict__ src,
                             float* __restrict__ deg, int E) {
    int e = blockIdx.x * blockDim.x + threadIdx.x;
    if (e < E) atomicAdd(&deg[src[e]], 1.0f);
}

__global__ void edge_kernel_h2(const float2* __restrict__ f2,
                               const float* __restrict__ w,
                               const int* __restrict__ src,
                               const int* __restrict__ dst,
                               const float* __restrict__ deg,
                               __half2* __restrict__ trans, int E) {
    long long t = (long long)blockIdx.x * blockDim.x + threadIdx.x;
    int e = (int)(t >> 4);
    int qp = (int)(t & 15);
    if (e >= E) return;
    int s = src[e];
    int d = dst[e];
    float coef = w[e] / fmaxf(deg[s], 1.0f);
    float2 fs = f2[s * QP + qp];
    float2 fd = f2[d * QP + qp];
    float xi0 = (75.0f / 31.0f) * (float)(2 * qp);
    float xi1 = (75.0f / 31.0f) * (float)(2 * qp + 1);
    float m0 = coef * xi0 * (fmaxf(fd.x, 0.0f) - fmaxf(fs.x, 0.0f));
    float m1 = coef * xi1 * (fmaxf(fd.y, 0.0f) - fmaxf(fs.y, 0.0f));
    unsafeAtomicAdd(&trans[s * QP + qp], __floats2half2_rn(m0, m1));
    unsafeAtomicAdd(&trans[d * QP + qp], __floats2half2_rn(-m0, -m1));
}

__global__ void final_h2(const float2* __restrict__ fdist,
                         const float2* __restrict__ coll,
                         const float2* __restrict__ srct,
                         const __half2* __restrict__ trans,
                         float2* __restrict__ out, int n2) {
    int i = blockIdx.x * blockDim.x + threadIdx.x;
    if (i >= n2) return;
    float2 tv = __half22float2(trans[i]);
    float2 fr = fdist[i];
    float2 cl = coll[i];
    float2 st = srct[i];
    float2 o;
    o.x = fmaxf(fmaxf(fr.x, 0.0f) - DT_C * (tv.x - cl.x - st.x), 0.0f);
    o.y = fmaxf(fmaxf(fr.y, 0.0f) - DT_C * (tv.y - cl.y - st.y), 0.0f);
    out[i] = o;
}

// ---------------- launch ----------------

extern "C" void kernel_launch(void* const* d_in, const int* in_sizes, int n_in,
                              void* d_out, int out_size, void* d_ws, size_t ws_size,
                              hipStream_t stream) {
    const float* f    = (const float*)d_in[0];
    const float* coll = (const float*)d_in[1];
    const float* srct = (const float*)d_in[2];
    const float* w    = (const float*)d_in[3];
    const int*   src  = (const int*)d_in[4];
    const int*   dst  = (const int*)d_in[5];
    float* out = (float*)d_out;

    const int N = N_NODES;
    const int E = N_EDGES;

    const size_t KEYS_BYTES = (size_t)NB * CAP * sizeof(unsigned int);  // 28.8 MB
    const size_t COEF_BYTES = (size_t)NB * CAP * sizeof(__half);        // 14.4 MB
    const size_t FH_BYTES   = (size_t)N * QCH * sizeof(__half);         // 6.4 MB
    const size_t CSUM_BYTES = (size_t)N * sizeof(float);
    const size_t DEG_BYTES  = (size_t)N * sizeof(unsigned int);
    const size_t GCUR_BYTES = (size_t)NB * sizeof(unsigned int);
    const size_t NEEDED = KEYS_BYTES + COEF_BYTES + FH_BYTES +
                          CSUM_BYTES + DEG_BYTES + GCUR_BYTES;

    if (ws_size >= NEEDED) {
        char* p = (char*)d_ws;
        unsigned int* keys  = (unsigned int*)p;            p += KEYS_BYTES;
        __half*       coefs = (__half*)p;                  p += COEF_BYTES;
        __half*       fh    = (__half*)p;                  p += FH_BYTES;
        float*        csum  = (float*)p;                   p += CSUM_BYTES;
        unsigned int* deg   = (unsigned int*)p;            p += DEG_BYTES;
        unsigned int* gcur  = (unsigned int*)p;

        // zero csum + deg + gcur (contiguous tail)
        hipMemsetAsync(csum, 0, CSUM_BYTES + DEG_BYTES + GCUR_BYTES, stream);

        deg_kernel_u32<<<(E + 255) / 256, 256, 0, stream>>>(src, deg, E);
        int n2 = N * QP;
        fh_kernel<<<(n2 + 255) / 256, 256, 0, stream>>>((const float2*)f,
                                                        (__half2*)fh, n2);
        bin_kernel<<<BIN_BLOCKS, 256, 0, stream>>>(src, dst, w, deg, gcur,
                                                   keys, coefs, csum, E);
        pad_kernel<<<NB, 128, 0, stream>>>(gcur, keys, coefs);
        gather_kernel<<<NB, 256, 0, stream>>>(f, fh, coll, srct, gcur, keys,
                                              coefs, csum, out);
    } else {
        // fallback: r2 packed-fp16 atomic path (496 us known-good)
        __half2* trans = (__half2*)d_ws;
        float* deg = (float*)((char*)d_ws + (size_t)N * QP * sizeof(__half2));
        hipMemsetAsync(trans, 0, (size_t)N * QP * sizeof(__half2), stream);
        hipMemsetAsync(deg, 0, (size_t)N * sizeof(float), stream);
        deg_kernel_f<<<(E + 255) / 256, 256, 0, stream>>>(src, deg, E);
        long long total = (long long)E * QP;
        int blocks = (int)((total + 255) / 256);
        edge_kernel_h2<<<blocks, 256, 0, stream>>>((const float2*)f, w, src, dst,
                                                   deg, trans, E);
        int n2 = N * QP;
        final_h2<<<(n2 + 255) / 256, 256, 0, stream>>>((const float2*)f,
                                                       (const float2*)coll,
                                                       (const float2*)srct,
                                                       trans, (float2*)out, n2);
    }
}

// Round 8
// 852.428 us; speedup vs baseline: 1.9859x; 1.9859x over previous
//
#include <hip/hip_runtime.h>
#include <stdint.h>

#define N_NODES 100000
#define N_EDGES 3200000
#define QCH 32
#define QP 16                       // u64 slots per node (2 channels each)
#define DT_C 0.1f

#define FIX_S 4194304.0f            // 2^22 scale
#define FIX_INV (1.0f / 4194304.0f)
#define FIX_B 8388608               // 2^23 per-term bias (keeps every field-term positive)

// Kernel 1: packed degree/incidence. high32 = out-degree, low32 = incidence count.
__global__ void degcnt_kernel(const int* __restrict__ src,
                              const int* __restrict__ dst,
                              unsigned long long* __restrict__ dc, int E) {
    int e = blockIdx.x * blockDim.x + threadIdx.x;
    if (e < E) {
        atomicAdd(&dc[src[e]], (1ULL << 32) | 1ULL);  // deg+1, inc+1
        atomicAdd(&dc[dst[e]], 1ULL);                 // inc+1
    }
}

// Kernel 2: one thread per (edge, u64-slot). Each u64 atomic carries TWO
// channels as biased 32-bit fixed-point fields -> 51.2M atomic ops total
// (half of the r2 pk_f16 path). xi is factored out (applied in finalize).
__global__ void edge_kernel_u64(const float2* __restrict__ f2,
                                const float* __restrict__ w,
                                const int* __restrict__ src,
                                const int* __restrict__ dst,
                                const unsigned long long* __restrict__ dc,
                                unsigned long long* __restrict__ acc, int E) {
    long long t = (long long)blockIdx.x * blockDim.x + threadIdx.x;
    int e = (int)(t >> 4);
    int j = (int)(t & 15);          // slot: channels 2j, 2j+1
    if (e >= E) return;
    int s = src[e];
    int d = dst[e];
    unsigned int deg = (unsigned int)(dc[s] >> 32);
    float c = w[e] / fmaxf((float)deg, 1.0f);
    float2 fs = f2[s * QP + j];
    float2 fd = f2[d * QP + j];
    float m0 = c * (fmaxf(fd.x, 0.0f) - fmaxf(fs.x, 0.0f));   // |m| < 1
    float m1 = c * (fmaxf(fd.y, 0.0f) - fmaxf(fs.y, 0.0f));
    int a0 = __float2int_rn(m0 * FIX_S);                      // |a| <= 2^22
    int a1 = __float2int_rn(m1 * FIX_S);
    // outflow at src: +m ; inflow at dst subtracted: -m. Bias B added per term.
    unsigned long long addp = ((unsigned long long)(unsigned int)(a1 + FIX_B) << 32)
                              | (unsigned int)(a0 + FIX_B);
    unsigned long long addn = ((unsigned long long)(unsigned int)(FIX_B - a1) << 32)
                              | (unsigned int)(FIX_B - a0);
    atomicAdd(&acc[(size_t)s * QP + j], addp);
    atomicAdd(&acc[(size_t)d * QP + j], addn);
}

// Kernel 3: unbias + scale + finalize. One thread per (node, slot).
__global__ void final_u64(const float2* __restrict__ fdist,
                          const float2* __restrict__ coll,
                          const float2* __restrict__ srct,
                          const unsigned long long* __restrict__ acc,
                          const unsigned long long* __restrict__ dc,
                          float2* __restrict__ out, int n2) {
    int i = blockIdx.x * blockDim.x + threadIdx.x;
    if (i >= n2) return;
    int node = i >> 4;
    int j = i & 15;
    unsigned long long a = acc[i];
    long long inc = (long long)(unsigned int)dc[node];        // low32 = incidence
    long long bias = inc * (long long)FIX_B;
    float v0 = (float)((long long)(a & 0xffffffffULL) - bias) * FIX_INV;
    float v1 = (float)((long long)(a >> 32) - bias) * FIX_INV;
    float xi0 = (75.0f / 31.0f) * (float)(2 * j);
    float xi1 = (75.0f / 31.0f) * (float)(2 * j + 1);
    float2 fr = fdist[i];
    float2 cl = coll[i];
    float2 st = srct[i];
    float f0 = fmaxf(fr.x, 0.0f);
    float f1 = fmaxf(fr.y, 0.0f);
    float2 o;
    o.x = fmaxf(f0 - DT_C * (xi0 * v0 - cl.x - st.x), 0.0f);
    o.y = fmaxf(f1 - DT_C * (xi1 * v1 - cl.y - st.y), 0.0f);
    out[i] = o;
}

extern "C" void kernel_launch(void* const* d_in, const int* in_sizes, int n_in,
                              void* d_out, int out_size, void* d_ws, size_t ws_size,
                              hipStream_t stream) {
    const float* f    = (const float*)d_in[0];  // [N, Q]
    const float* coll = (const float*)d_in[1];  // [N, Q]
    const float* srct = (const float*)d_in[2];  // [N, Q]
    const float* w    = (const float*)d_in[3];  // [E]
    const int*   src  = (const int*)d_in[4];    // [E]
    const int*   dst  = (const int*)d_in[5];    // [E]
    float* out = (float*)d_out;                 // [N, Q]

    const int N = N_NODES;
    const int E = N_EDGES;

    // ws: u64 acc[N*QP] (12.8 MB) then u64 dc[N] (0.8 MB), zeroed together
    unsigned long long* acc = (unsigned long long*)d_ws;
    unsigned long long* dc  = acc + (size_t)N * QP;
    hipMemsetAsync(d_ws, 0, (size_t)(N * QP + N) * sizeof(unsigned long long), stream);

    degcnt_kernel<<<(E + 255) / 256, 256, 0, stream>>>(src, dst, dc, E);

    long long total = (long long)E * QP;
    int blocks = (int)((total + 255) / 256);
    edge_kernel_u64<<<blocks, 256, 0, stream>>>((const float2*)f, w, src, dst,
                                                dc, acc, E);

    int n2 = N * QP;
    final_u64<<<(n2 + 255) / 256, 256, 0, stream>>>((const float2*)f,
                                                    (const float2*)coll,
                                                    (const float2*)srct,
                                                    acc, dc, (float2*)out, n2);
}

// Round 9
// 497.105 us; speedup vs baseline: 3.4054x; 1.7148x over previous
//
#include <hip/hip_runtime.h>
#include <hip/hip_fp16.h>

#define N_NODES 100000
#define N_EDGES 3200000
#define QCH 32
#define QP (QCH / 2)          // 16 half2 pairs per node
#define DT_C 0.1f

// Kernel 1: out-degree of each node (float, matches segment_sum of ones)
__global__ void deg_kernel(const int* __restrict__ src,
                           float* __restrict__ deg, int E) {
    int e = blockIdx.x * blockDim.x + threadIdx.x;
    if (e < E) atomicAdd(&deg[src[e]], 1.0f);
}

// Kernel 1b: fp16 relu'd copy of f — halves edge-kernel gather bytes
// (64 B/row vs 128 B) and nearly fits per-XCD L2 (6.4 MB vs 4 MB).
__global__ void fh_kernel(const float2* __restrict__ f2,
                          __half2* __restrict__ fh, int n2) {
    int i = blockIdx.x * blockDim.x + threadIdx.x;
    if (i < n2) {
        float2 v = f2[i];
        fh[i] = __floats2half2_rn(fmaxf(v.x, 0.0f), fmaxf(v.y, 0.0f));
    }
}

// Kernel 2: one thread per (edge, q-pair). Reads fp16 rows, packs two
// xi-scaled messages into one pk_f16 atomic per endpoint (4 B each —
// the byte-optimal atomic primitive on gfx950).
__global__ void edge_kernel_h2(const __half2* __restrict__ fh,
                               const float* __restrict__ w,
                               const int* __restrict__ src,
                               const int* __restrict__ dst,
                               const float* __restrict__ deg,
                               __half2* __restrict__ trans, int E) {
    long long t = (long long)blockIdx.x * blockDim.x + threadIdx.x;
    int e = (int)(t >> 4);
    int qp = (int)(t & 15);
    if (e >= E) return;
    int s = src[e];
    int d = dst[e];
    float coef = w[e] / fmaxf(deg[s], 1.0f);
    float2 fs = __half22float2(fh[s * QP + qp]);   // already relu'd
    float2 fd = __half22float2(fh[d * QP + qp]);
    float xi0 = (75.0f / 31.0f) * (float)(2 * qp);
    float xi1 = (75.0f / 31.0f) * (float)(2 * qp + 1);
    float m0 = coef * xi0 * (fd.x - fs.x);
    float m1 = coef * xi1 * (fd.y - fs.y);
    unsafeAtomicAdd(&trans[s * QP + qp], __floats2half2_rn(m0, m1));   // outflow
    unsafeAtomicAdd(&trans[d * QP + qp], __floats2half2_rn(-m0, -m1)); // -inflow
}

// Kernel 3: finalize, one thread per q-pair, float2 output writes.
__global__ void final_h2(const float2* __restrict__ fdist,
                         const float2* __restrict__ coll,
                         const float2* __restrict__ srct,
                         const __half2* __restrict__ trans,
                         float2* __restrict__ out, int n2) {
    int i = blockIdx.x * blockDim.x + threadIdx.x;
    if (i >= n2) return;
    float2 tv = __half22float2(trans[i]);
    float2 fr = fdist[i];
    float2 cl = coll[i];
    float2 st = srct[i];
    float2 o;
    o.x = fmaxf(fmaxf(fr.x, 0.0f) - DT_C * (tv.x - cl.x - st.x), 0.0f);
    o.y = fmaxf(fmaxf(fr.y, 0.0f) - DT_C * (tv.y - cl.y - st.y), 0.0f);
    out[i] = o;
}

extern "C" void kernel_launch(void* const* d_in, const int* in_sizes, int n_in,
                              void* d_out, int out_size, void* d_ws, size_t ws_size,
                              hipStream_t stream) {
    const float* f    = (const float*)d_in[0];  // [N, Q]
    const float* coll = (const float*)d_in[1];  // [N, Q]
    const float* srct = (const float*)d_in[2];  // [N, Q]
    const float* w    = (const float*)d_in[3];  // [E]
    const int*   src  = (const int*)d_in[4];    // [E]
    const int*   dst  = (const int*)d_in[5];    // [E]
    float* out = (float*)d_out;                 // [N, Q]

    const int N = N_NODES;
    const int E = N_EDGES;

    // ws layout: half2 trans[N*QP] (6.4 MB) | float deg[N] (0.4 MB)
    //            | half2 fh[N*QP] (6.4 MB)
    __half2* trans = (__half2*)d_ws;
    float*   deg   = (float*)((char*)d_ws + (size_t)N * QP * sizeof(__half2));
    __half2* fh    = (__half2*)((char*)deg + (size_t)N * sizeof(float));

    // zero trans + deg (contiguous); fh fully overwritten by fh_kernel
    hipMemsetAsync(d_ws, 0,
                   (size_t)N * QP * sizeof(__half2) + (size_t)N * sizeof(float),
                   stream);

    int n2 = N * QP;
    deg_kernel<<<(E + 255) / 256, 256, 0, stream>>>(src, deg, E);
    fh_kernel<<<(n2 + 255) / 256, 256, 0, stream>>>((const float2*)f, fh, n2);

    long long total = (long long)E * QP;
    int blocks = (int)((total + 255) / 256);
    edge_kernel_h2<<<blocks, 256, 0, stream>>>(fh, w, src, dst, deg, trans, E);

    final_h2<<<(n2 + 255) / 256, 256, 0, stream>>>((const float2*)f,
                                                   (const float2*)coll,
                                                   (const float2*)srct,
                                                   trans, (float2*)out, n2);
}

// Round 10
// 402.419 us; speedup vs baseline: 4.2067x; 1.2353x over previous
//
#include <hip/hip_runtime.h>
#include <hip/hip_fp16.h>

#define N_NODES 100000
#define N_EDGES 3200000
#define QCH 32
#define QP 16                   // half2 pairs per node
#define DT_C 0.1f

#define NCHUNK 64
#define CHUNK_E (N_EDGES / NCHUNK)   // 50000
#define HALF_NODES 50000
#define WORDS_HALF 12500             // HALF_NODES/4 (u8-packed u32 words)
#define WORDS_TOT 25000              // N_NODES/4

// ---- degree via contention-free LDS histogram (no global atomics) ----
// 128 blocks = 64 edge-chunks x 2 node-halves. Each block builds a byte-packed
// histogram of src[] in LDS, then writes its private partial (coalesced).
__global__ __launch_bounds__(256) void hist_kernel(const int* __restrict__ src,
                                                   unsigned int* __restrict__ part) {
    __shared__ unsigned int h[WORDS_HALF];     // 50 KB
    int tid = threadIdx.x;
    int chunk = blockIdx.x >> 1;
    int rh = blockIdx.x & 1;
    int r0 = rh * HALF_NODES;
    for (int i = tid; i < WORDS_HALF; i += 256) h[i] = 0u;
    __syncthreads();
    int e0 = chunk * CHUNK_E;
    for (int e = e0 + tid; e < e0 + CHUNK_E; e += 256) {
        int n = src[e] - r0;
        if ((unsigned)n < HALF_NODES)
            atomicAdd(&h[n >> 2], 1u << (8 * (n & 3)));   // byte-packed count
    }
    __syncthreads();
    unsigned int* dstp = part + (size_t)chunk * WORDS_TOT + rh * WORDS_HALF;
    for (int i = tid; i < WORDS_HALF; i += 256) dstp[i] = h[i];
}

// Sum the 64 byte-packed partials -> float out-degree. Streaming, coalesced.
__global__ void degsum_kernel(const unsigned int* __restrict__ part,
                              float* __restrict__ deg) {
    int w = blockIdx.x * blockDim.x + threadIdx.x;
    if (w >= WORDS_TOT) return;
    unsigned int s0 = 0, s1 = 0, s2 = 0, s3 = 0;
#pragma unroll 8
    for (int i = 0; i < NCHUNK; ++i) {
        unsigned int v = part[(size_t)i * WORDS_TOT + w];
        s0 += v & 255u;
        s1 += (v >> 8) & 255u;
        s2 += (v >> 16) & 255u;
        s3 += v >> 24;
    }
    *(float4*)(deg + 4 * w) =
        make_float4((float)s0, (float)s1, (float)s2, (float)s3);
}

// fp16 relu'd copy of f (halves edge-kernel gather bytes, hoists relu)
__global__ void fh_kernel(const float2* __restrict__ f2,
                          __half2* __restrict__ fh, int n2) {
    int i = blockIdx.x * blockDim.x + threadIdx.x;
    if (i < n2) {
        float2 v = f2[i];
        fh[i] = __floats2half2_rn(fmaxf(v.x, 0.0f), fmaxf(v.y, 0.0f));
    }
}

// Edge scatter: one thread per (edge, q-pair); one 4B pk_f16 atomic per
// endpoint (byte-optimal). Bound by atomic write-through @ ~1.3 TB/s.
__global__ void edge_kernel_h2(const __half2* __restrict__ fh,
                               const float* __restrict__ w,
                               const int* __restrict__ src,
                               const int* __restrict__ dst,
                               const float* __restrict__ deg,
                               __half2* __restrict__ trans, int E) {
    long long t = (long long)blockIdx.x * blockDim.x + threadIdx.x;
    int e = (int)(t >> 4);
    int qp = (int)(t & 15);
    if (e >= E) return;
    int s = src[e];
    int d = dst[e];
    float coef = w[e] / fmaxf(deg[s], 1.0f);
    float2 fs = __half22float2(fh[s * QP + qp]);   // already relu'd
    float2 fd = __half22float2(fh[d * QP + qp]);
    float xi0 = (75.0f / 31.0f) * (float)(2 * qp);
    float xi1 = (75.0f / 31.0f) * (float)(2 * qp + 1);
    float m0 = coef * xi0 * (fd.x - fs.x);
    float m1 = coef * xi1 * (fd.y - fs.y);
    unsafeAtomicAdd(&trans[s * QP + qp], __floats2half2_rn(m0, m1));   // outflow
    unsafeAtomicAdd(&trans[d * QP + qp], __floats2half2_rn(-m0, -m1)); // -inflow
}

// Finalize, one thread per q-pair, float2 writes.
__global__ void final_h2(const float2* __restrict__ fdist,
                         const float2* __restrict__ coll,
                         const float2* __restrict__ srct,
                         const __half2* __restrict__ trans,
                         float2* __restrict__ out, int n2) {
    int i = blockIdx.x * blockDim.x + threadIdx.x;
    if (i >= n2) return;
    float2 tv = __half22float2(trans[i]);
    float2 fr = fdist[i];
    float2 cl = coll[i];
    float2 st = srct[i];
    float2 o;
    o.x = fmaxf(fmaxf(fr.x, 0.0f) - DT_C * (tv.x - cl.x - st.x), 0.0f);
    o.y = fmaxf(fmaxf(fr.y, 0.0f) - DT_C * (tv.y - cl.y - st.y), 0.0f);
    out[i] = o;
}

// fallback deg (atomic) if ws ever too small for partials
__global__ void deg_kernel_f(const int* __restrict__ src,
                             float* __restrict__ deg, int E) {
    int e = blockIdx.x * blockDim.x + threadIdx.x;
    if (e < E) atomicAdd(&deg[src[e]], 1.0f);
}

extern "C" void kernel_launch(void* const* d_in, const int* in_sizes, int n_in,
                              void* d_out, int out_size, void* d_ws, size_t ws_size,
                              hipStream_t stream) {
    const float* f    = (const float*)d_in[0];  // [N, Q]
    const float* coll = (const float*)d_in[1];  // [N, Q]
    const float* srct = (const float*)d_in[2];  // [N, Q]
    const float* w    = (const float*)d_in[3];  // [E]
    const int*   src  = (const int*)d_in[4];    // [E]
    const int*   dst  = (const int*)d_in[5];    // [E]
    float* out = (float*)d_out;                 // [N, Q]

    const int N = N_NODES;
    const int E = N_EDGES;

    // ws: half2 trans[N*QP] (6.4MB) | float deg[N] (0.4MB)
    //     | half2 fh[N*QP] (6.4MB) | u32 part[NCHUNK*WORDS_TOT] (6.4MB)
    const size_t TRANS_B = (size_t)N * QP * sizeof(__half2);
    const size_t DEG_B   = (size_t)N * sizeof(float);
    const size_t FH_B    = (size_t)N * QP * sizeof(__half2);
    const size_t PART_B  = (size_t)NCHUNK * WORDS_TOT * sizeof(unsigned int);

    __half2* trans = (__half2*)d_ws;
    float*   deg   = (float*)((char*)d_ws + TRANS_B);
    __half2* fh    = (__half2*)((char*)deg + DEG_B);
    unsigned int* part = (unsigned int*)((char*)fh + FH_B);

    int n2 = N * QP;

    // zero trans only (deg/fh/part fully overwritten)
    hipMemsetAsync(trans, 0, TRANS_B, stream);

    if (ws_size >= TRANS_B + DEG_B + FH_B + PART_B) {
        hist_kernel<<<2 * NCHUNK, 256, 0, stream>>>(src, part);
        degsum_kernel<<<(WORDS_TOT + 255) / 256, 256, 0, stream>>>(part, deg);
    } else {
        hipMemsetAsync(deg, 0, DEG_B, stream);
        deg_kernel_f<<<(E + 255) / 256, 256, 0, stream>>>(src, deg, E);
    }

    fh_kernel<<<(n2 + 255) / 256, 256, 0, stream>>>((const float2*)f, fh, n2);

    long long total = (long long)E * QP;
    int blocks = (int)((total + 255) / 256);
    edge_kernel_h2<<<blocks, 256, 0, stream>>>(fh, w, src, dst, deg, trans, E);

    final_h2<<<(n2 + 255) / 256, 256, 0, stream>>>((const float2*)f,
                                                   (const float2*)coll,
                                                   (const float2*)srct,
                                                   trans, (float2*)out, n2);
}

// Round 11
// 365.763 us; speedup vs baseline: 4.6282x; 1.1002x over previous
//
#include <hip/hip_runtime.h>
#include <hip/hip_fp16.h>

#define N_NODES 100000
#define N_EDGES 3200000
#define QCH 32
#define QP 16                   // half2 pairs per node
#define DT_C 0.1f

#define NCHUNK 256
#define CHUNK_E (N_EDGES / NCHUNK)   // 12500
#define HALF_NODES 50000
#define WORDS_HALF 12500             // HALF_NODES/4 (u8-packed u32 words)
#define WORDS_TOT 25000              // N_NODES/4

// ---- degree via contention-free LDS histogram (no global atomics) ----
// 512 blocks = 256 edge-chunks x 2 node-halves (full CU occupancy).
__global__ __launch_bounds__(256) void hist_kernel(const int* __restrict__ src,
                                                   unsigned int* __restrict__ part) {
    __shared__ unsigned int h[WORDS_HALF];     // 50 KB
    int tid = threadIdx.x;
    int chunk = blockIdx.x >> 1;
    int rh = blockIdx.x & 1;
    int r0 = rh * HALF_NODES;
    for (int i = tid; i < WORDS_HALF; i += 256) h[i] = 0u;
    __syncthreads();
    int e0 = chunk * CHUNK_E;
    for (int e = e0 + tid; e < e0 + CHUNK_E; e += 256) {
        int n = src[e] - r0;
        if ((unsigned)n < HALF_NODES)
            atomicAdd(&h[n >> 2], 1u << (8 * (n & 3)));   // byte-packed count
    }
    __syncthreads();
    unsigned int* dstp = part + (size_t)chunk * WORDS_TOT + rh * WORDS_HALF;
    for (int i = tid; i < WORDS_HALF; i += 256) dstp[i] = h[i];
}

#define DEG_BLOCKS 98            // ceil(25000/256)

// Fused prep: blocks [0,DEG_BLOCKS) sum byte-packed partials -> float deg;
// remaining blocks build the relu'd fp16 copy of f.
__global__ __launch_bounds__(256) void prep_kernel(
        const unsigned int* __restrict__ part,
        float* __restrict__ deg,
        const float2* __restrict__ f2,
        __half2* __restrict__ fh, int n2) {
    if (blockIdx.x < DEG_BLOCKS) {
        int wd = blockIdx.x * 256 + threadIdx.x;
        if (wd >= WORDS_TOT) return;
        unsigned int s0 = 0, s1 = 0, s2 = 0, s3 = 0;
#pragma unroll 8
        for (int i = 0; i < NCHUNK; ++i) {
            unsigned int v = part[(size_t)i * WORDS_TOT + wd];
            s0 += v & 255u;
            s1 += (v >> 8) & 255u;
            s2 += (v >> 16) & 255u;
            s3 += v >> 24;
        }
        *(float4*)(deg + 4 * wd) =
            make_float4((float)s0, (float)s1, (float)s2, (float)s3);
    } else {
        int i = (blockIdx.x - DEG_BLOCKS) * 256 + threadIdx.x;
        if (i < n2) {
            float2 v = f2[i];
            fh[i] = __floats2half2_rn(fmaxf(v.x, 0.0f), fmaxf(v.y, 0.0f));
        }
    }
}

// Edge scatter: one thread per (edge, q-pair); one 4B pk_f16 atomic per
// endpoint. At the 32-bit-atomic-op wall (~328 G ops/s) — proven floor.
__global__ void edge_kernel_h2(const __half2* __restrict__ fh,
                               const float* __restrict__ w,
                               const int* __restrict__ src,
                               const int* __restrict__ dst,
                               const float* __restrict__ deg,
                               __half2* __restrict__ trans, int E) {
    long long t = (long long)blockIdx.x * blockDim.x + threadIdx.x;
    int e = (int)(t >> 4);
    int qp = (int)(t & 15);
    if (e >= E) return;
    int s = src[e];
    int d = dst[e];
    float coef = w[e] / fmaxf(deg[s], 1.0f);
    float2 fs = __half22float2(fh[s * QP + qp]);   // already relu'd
    float2 fd = __half22float2(fh[d * QP + qp]);
    float xi0 = (75.0f / 31.0f) * (float)(2 * qp);
    float xi1 = (75.0f / 31.0f) * (float)(2 * qp + 1);
    float m0 = coef * xi0 * (fd.x - fs.x);
    float m1 = coef * xi1 * (fd.y - fs.y);
    unsafeAtomicAdd(&trans[s * QP + qp], __floats2half2_rn(m0, m1));   // outflow
    unsafeAtomicAdd(&trans[d * QP + qp], __floats2half2_rn(-m0, -m1)); // -inflow
}

// Finalize, float4-vectorized: one thread per 4 channels.
__global__ void final_f4(const float4* __restrict__ fdist,
                         const float4* __restrict__ coll,
                         const float4* __restrict__ srct,
                         const __half2* __restrict__ trans,
                         float4* __restrict__ out, int n4) {
    int i = blockIdx.x * blockDim.x + threadIdx.x;
    if (i >= n4) return;
    float2 t0 = __half22float2(trans[2 * i]);
    float2 t1 = __half22float2(trans[2 * i + 1]);
    float4 fr = fdist[i];
    float4 cl = coll[i];
    float4 st = srct[i];
    float4 o;
    o.x = fmaxf(fmaxf(fr.x, 0.0f) - DT_C * (t0.x - cl.x - st.x), 0.0f);
    o.y = fmaxf(fmaxf(fr.y, 0.0f) - DT_C * (t0.y - cl.y - st.y), 0.0f);
    o.z = fmaxf(fmaxf(fr.z, 0.0f) - DT_C * (t1.x - cl.z - st.z), 0.0f);
    o.w = fmaxf(fmaxf(fr.w, 0.0f) - DT_C * (t1.y - cl.w - st.w), 0.0f);
    out[i] = o;
}

// fallback deg (atomic) if ws ever too small for partials
__global__ void deg_kernel_f(const int* __restrict__ src,
                             float* __restrict__ deg, int E) {
    int e = blockIdx.x * blockDim.x + threadIdx.x;
    if (e < E) atomicAdd(&deg[src[e]], 1.0f);
}

__global__ void fh_only_kernel(const float2* __restrict__ f2,
                               __half2* __restrict__ fh, int n2) {
    int i = blockIdx.x * blockDim.x + threadIdx.x;
    if (i < n2) {
        float2 v = f2[i];
        fh[i] = __floats2half2_rn(fmaxf(v.x, 0.0f), fmaxf(v.y, 0.0f));
    }
}

extern "C" void kernel_launch(void* const* d_in, const int* in_sizes, int n_in,
                              void* d_out, int out_size, void* d_ws, size_t ws_size,
                              hipStream_t stream) {
    const float* f    = (const float*)d_in[0];  // [N, Q]
    const float* coll = (const float*)d_in[1];  // [N, Q]
    const float* srct = (const float*)d_in[2];  // [N, Q]
    const float* w    = (const float*)d_in[3];  // [E]
    const int*   src  = (const int*)d_in[4];    // [E]
    const int*   dst  = (const int*)d_in[5];    // [E]
    float* out = (float*)d_out;                 // [N, Q]

    const int N = N_NODES;
    const int E = N_EDGES;

    // ws: half2 trans[N*QP] (6.4MB) | float deg[N] (0.4MB)
    //     | half2 fh[N*QP] (6.4MB) | u32 part[NCHUNK*WORDS_TOT] (25.6MB)
    const size_t TRANS_B = (size_t)N * QP * sizeof(__half2);
    const size_t DEG_B   = (size_t)N * sizeof(float);
    const size_t FH_B    = (size_t)N * QP * sizeof(__half2);
    const size_t PART_B  = (size_t)NCHUNK * WORDS_TOT * sizeof(unsigned int);

    __half2* trans = (__half2*)d_ws;
    float*   deg   = (float*)((char*)d_ws + TRANS_B);
    __half2* fh    = (__half2*)((char*)deg + DEG_B);
    unsigned int* part = (unsigned int*)((char*)fh + FH_B);

    int n2 = N * QP;

    // zero trans only (deg/fh/part fully overwritten)
    hipMemsetAsync(trans, 0, TRANS_B, stream);

    if (ws_size >= TRANS_B + DEG_B + FH_B + PART_B) {
        hist_kernel<<<2 * NCHUNK, 256, 0, stream>>>(src, part);
        int fh_blocks = (n2 + 255) / 256;
        prep_kernel<<<DEG_BLOCKS + fh_blocks, 256, 0, stream>>>(
            part, deg, (const float2*)f, fh, n2);
    } else {
        hipMemsetAsync(deg, 0, DEG_B, stream);
        deg_kernel_f<<<(E + 255) / 256, 256, 0, stream>>>(src, deg, E);
        fh_only_kernel<<<(n2 + 255) / 256, 256, 0, stream>>>((const float2*)f,
                                                             fh, n2);
    }

    long long total = (long long)E * QP;
    int blocks = (int)((total + 255) / 256);
    edge_kernel_h2<<<blocks, 256, 0, stream>>>(fh, w, src, dst, deg, trans, E);

    int n4 = N * QCH / 4;
    final_f4<<<(n4 + 255) / 256, 256, 0, stream>>>((const float4*)f,
                                                   (const float4*)coll,
                                                   (const float4*)srct,
                                                   trans, (float4*)out, n4);
}

// Round 12
// 364.357 us; speedup vs baseline: 4.6461x; 1.0039x over previous
//
#include <hip/hip_runtime.h>
#include <hip/hip_fp16.h>

#define N_NODES 100000
#define N_EDGES 3200000
#define QCH 32
#define QP 16                   // half2 pairs per node
#define DT_C 0.1f

#define NCHUNK 256
#define CHUNK_E (N_EDGES / NCHUNK)   // 12500
#define HALF_NODES 50000
#define WORDS_HALF 12500             // HALF_NODES/4 (u8-packed u32 words)
#define WORDS_TOT 25000              // N_NODES/4

// ---- degree via contention-free LDS histogram (no global atomics) ----
// 512 blocks = 256 edge-chunks x 2 node-halves.
__global__ __launch_bounds__(256) void hist_kernel(const int* __restrict__ src,
                                                   unsigned int* __restrict__ part) {
    __shared__ unsigned int h[WORDS_HALF];     // 50 KB
    int tid = threadIdx.x;
    int chunk = blockIdx.x >> 1;
    int rh = blockIdx.x & 1;
    int r0 = rh * HALF_NODES;
    for (int i = tid; i < WORDS_HALF; i += 256) h[i] = 0u;
    __syncthreads();
    int e0 = chunk * CHUNK_E;
    for (int e = e0 + tid; e < e0 + CHUNK_E; e += 256) {
        int n = src[e] - r0;
        if ((unsigned)n < HALF_NODES)
            atomicAdd(&h[n >> 2], 1u << (8 * (n & 3)));   // byte-packed count
    }
    __syncthreads();
    unsigned int* dstp = part + (size_t)chunk * WORDS_TOT + rh * WORDS_HALF;
    for (int i = tid; i < WORDS_HALF; i += 256) dstp[i] = h[i];
}

// Sum the byte-packed partials -> float out-degree. 98 blocks, coalesced.
__global__ __launch_bounds__(256) void degsum_kernel(
        const unsigned int* __restrict__ part, float* __restrict__ deg) {
    int wd = blockIdx.x * 256 + threadIdx.x;
    if (wd >= WORDS_TOT) return;
    unsigned int s0 = 0, s1 = 0, s2 = 0, s3 = 0;
#pragma unroll 8
    for (int i = 0; i < NCHUNK; ++i) {
        unsigned int v = part[(size_t)i * WORDS_TOT + wd];
        s0 += v & 255u;
        s1 += (v >> 8) & 255u;
        s2 += (v >> 16) & 255u;
        s3 += v >> 24;
    }
    *(float4*)(deg + 4 * wd) =
        make_float4((float)s0, (float)s1, (float)s2, (float)s3);
}

// Edge scatter (r2's proven kernel): one thread per (edge, q-pair); one 4B
// pk_f16 atomic per endpoint. At the atomic write-through wall (~1.3 TB/s
// over 400 MB) — structural floor for this op.
__global__ void edge_kernel_h2(const float2* __restrict__ f2,
                               const float* __restrict__ w,
                               const int* __restrict__ src,
                               const int* __restrict__ dst,
                               const float* __restrict__ deg,
                               __half2* __restrict__ trans, int E) {
    long long t = (long long)blockIdx.x * blockDim.x + threadIdx.x;
    int e = (int)(t >> 4);
    int qp = (int)(t & 15);
    if (e >= E) return;
    int s = src[e];
    int d = dst[e];
    float coef = w[e] / fmaxf(deg[s], 1.0f);
    float2 fs = f2[s * QP + qp];
    float2 fd = f2[d * QP + qp];
    float xi0 = (75.0f / 31.0f) * (float)(2 * qp);
    float xi1 = (75.0f / 31.0f) * (float)(2 * qp + 1);
    float m0 = coef * xi0 * (fmaxf(fd.x, 0.0f) - fmaxf(fs.x, 0.0f));
    float m1 = coef * xi1 * (fmaxf(fd.y, 0.0f) - fmaxf(fs.y, 0.0f));
    unsafeAtomicAdd(&trans[s * QP + qp], __floats2half2_rn(m0, m1));   // outflow
    unsafeAtomicAdd(&trans[d * QP + qp], __floats2half2_rn(-m0, -m1)); // -inflow
}

// Finalize, float4-vectorized: one thread per 4 channels.
__global__ void final_f4(const float4* __restrict__ fdist,
                         const float4* __restrict__ coll,
                         const float4* __restrict__ srct,
                         const __half2* __restrict__ trans,
                         float4* __restrict__ out, int n4) {
    int i = blockIdx.x * blockDim.x + threadIdx.x;
    if (i >= n4) return;
    float2 t0 = __half22float2(trans[2 * i]);
    float2 t1 = __half22float2(trans[2 * i + 1]);
    float4 fr = fdist[i];
    float4 cl = coll[i];
    float4 st = srct[i];
    float4 o;
    o.x = fmaxf(fmaxf(fr.x, 0.0f) - DT_C * (t0.x - cl.x - st.x), 0.0f);
    o.y = fmaxf(fmaxf(fr.y, 0.0f) - DT_C * (t0.y - cl.y - st.y), 0.0f);
    o.z = fmaxf(fmaxf(fr.z, 0.0f) - DT_C * (t1.x - cl.z - st.z), 0.0f);
    o.w = fmaxf(fmaxf(fr.w, 0.0f) - DT_C * (t1.y - cl.w - st.w), 0.0f);
    out[i] = o;
}

// fallback deg (global atomics) if ws ever too small for partials
__global__ void deg_kernel_f(const int* __restrict__ src,
                             float* __restrict__ deg, int E) {
    int e = blockIdx.x * blockDim.x + threadIdx.x;
    if (e < E) atomicAdd(&deg[src[e]], 1.0f);
}

extern "C" void kernel_launch(void* const* d_in, const int* in_sizes, int n_in,
                              void* d_out, int out_size, void* d_ws, size_t ws_size,
                              hipStream_t stream) {
    const float* f    = (const float*)d_in[0];  // [N, Q]
    const float* coll = (const float*)d_in[1];  // [N, Q]
    const float* srct = (const float*)d_in[2];  // [N, Q]
    const float* w    = (const float*)d_in[3];  // [E]
    const int*   src  = (const int*)d_in[4];    // [E]
    const int*   dst  = (const int*)d_in[5];    // [E]
    float* out = (float*)d_out;                 // [N, Q]

    const int N = N_NODES;
    const int E = N_EDGES;

    // ws: half2 trans[N*QP] (6.4MB) | float deg[N] (0.4MB)
    //     | u32 part[NCHUNK*WORDS_TOT] (25.6MB)
    const size_t TRANS_B = (size_t)N * QP * sizeof(__half2);
    const size_t DEG_B   = (size_t)N * sizeof(float);
    const size_t PART_B  = (size_t)NCHUNK * WORDS_TOT * sizeof(unsigned int);

    __half2* trans = (__half2*)d_ws;
    float*   deg   = (float*)((char*)d_ws + TRANS_B);
    unsigned int* part = (unsigned int*)((char*)deg + DEG_B);

    // zero trans (deg/part fully overwritten)
    hipMemsetAsync(trans, 0, TRANS_B, stream);

    if (ws_size >= TRANS_B + DEG_B + PART_B) {
        hist_kernel<<<2 * NCHUNK, 256, 0, stream>>>(src, part);
        degsum_kernel<<<(WORDS_TOT + 255) / 256, 256, 0, stream>>>(part, deg);
    } else {
        hipMemsetAsync(deg, 0, DEG_B, stream);
        deg_kernel_f<<<(E + 255) / 256, 256, 0, stream>>>(src, deg, E);
    }

    long long total = (long long)E * QP;
    int blocks = (int)((total + 255) / 256);
    edge_kernel_h2<<<blocks, 256, 0, stream>>>((const float2*)f, w, src, dst,
                                               deg, trans, E);

    int n4 = N * QCH / 4;
    final_f4<<<(n4 + 255) / 256, 256, 0, stream>>>((const float4*)f,
                                                   (const float4*)coll,
                                                   (const float4*)srct,
                                                   trans, (float4*)out, n4);
}